// Round 3
// baseline (263.113 us; speedup 1.0000x reference)
//
#include <hip/hip_runtime.h>
#include <hip/hip_bf16.h>
#include <math.h>

#define DIM 768
#define CA  192

typedef __attribute__((ext_vector_type(8))) short short8;
typedef __attribute__((ext_vector_type(4))) float f32x4;

static __device__ __forceinline__ short f2bf(float f) {
    union { __hip_bfloat16 b; short s; } u;
    u.b = __float2bfloat16(f);
    return u.s;
}
static __device__ __forceinline__ float gelu_exact(float x) {
    return 0.5f * x * (1.0f + erff(x * 0.70710678118654752440f));
}

// ---------------------------------------------------------------------------
// Prep: w1 (768,192) -> w1T (192,768) bf16; w2 (192,768) -> w2T (768,192) bf16
// ---------------------------------------------------------------------------
__global__ void prep_kernel(const float* __restrict__ w1, const float* __restrict__ w2,
                            short* __restrict__ w1T, short* __restrict__ w2T) {
    int idx = blockIdx.x * 256 + threadIdx.x;
    if (idx < CA * DIM) {
        int n = idx / DIM, k = idx - n * DIM;
        w1T[idx] = f2bf(w1[k * CA + n]);
        int n2 = idx / CA, k2 = idx - n2 * CA;
        w2T[idx] = f2bf(w2[k2 * DIM + n2]);
    }
}

// ---------------------------------------------------------------------------
// GEMM1 fused, zero-LDS zero-barrier. Each wave: 16 rows (one l, complete
// t-groups) x all 192 cols. A-frags loaded straight from x (fp32->bf16 cvt
// in regs), B-frags straight from w1T (L1/L2-resident, 295 KB).
// Fragment layout: lane lm = row/col index, lg*8 = k-chunk  [m89-verified].
// Register dbuf on A and B; no __syncthreads -> no vmcnt(0) drains.
// Grid 392 = 196 l * 2 row-halves; 4 independent waves per block.
// ---------------------------------------------------------------------------
__global__ __launch_bounds__(256) void gemm1_fused(
        const float* __restrict__ x, const short* __restrict__ w1T,
        const float* __restrict__ b1, const float* __restrict__ conv_w,
        const float* __restrict__ conv_b, short* __restrict__ gq) {
    const int bx   = blockIdx.x;            // 0..391
    const int l    = (bx >> 1) + 1;         // 1..196
    const int wave = threadIdx.x >> 6, lane = threadIdx.x & 63;
    const int R0   = l * 128 + (bx & 1) * 64 + wave * 16;
    const int lm   = lane & 15, lg = lane >> 4;

    const float* xA = x   + (size_t)(R0 + lm) * DIM + lg * 8;
    const short* wB = w1T + (size_t)lm * DIM + lg * 8;

    f32x4 acc[12] = {};

    f32x4 a0 = *(const f32x4*)xA;
    f32x4 a1 = *(const f32x4*)(xA + 4);
    short8 bcur[12];
    #pragma unroll
    for (int j = 0; j < 12; j++) bcur[j] = *(const short8*)(wB + (size_t)j * 16 * DIM);

    #pragma unroll 2
    for (int k = 0; k < 24; k++) {
        f32x4 a0n, a1n;
        short8 bnxt[12];
        if (k < 23) {
            const float* xn = xA + (k + 1) * 32;
            a0n = *(const f32x4*)xn;
            a1n = *(const f32x4*)(xn + 4);
            const short* wn = wB + (k + 1) * 32;
            #pragma unroll
            for (int j = 0; j < 12; j++) bnxt[j] = *(const short8*)(wn + (size_t)j * 16 * DIM);
        }
        short8 af;
        #pragma unroll
        for (int e = 0; e < 4; e++) { af[e] = f2bf(a0[e]); af[4 + e] = f2bf(a1[e]); }
        #pragma unroll
        for (int j = 0; j < 12; j++)
            acc[j] = __builtin_amdgcn_mfma_f32_16x16x32_bf16(af, bcur[j], acc[j], 0, 0, 0);
        a0 = a0n; a1 = a1n;
        #pragma unroll
        for (int j = 0; j < 12; j++) bcur[j] = bnxt[j];
    }

    // Epilogue: bias + temporal res (shfl_xor 16 over t-halves) + gelu -> bf16 g
    const int g1  = lg & 1;
    const int row = R0 + lg * 4;
    #pragma unroll
    for (int j = 0; j < 12; j++) {
        const int c = j * 16 + lm;
        const float b1c = b1[c];
        const float cw0 = conv_w[c * 3 + 0];
        const float cw1 = conv_w[c * 3 + 1];
        const float cw2 = conv_w[c * 3 + 2];
        const float cb  = conv_b[c];
        float hv[4];
        #pragma unroll
        for (int r = 0; r < 4; r++) hv[r] = acc[j][r] + b1c;
        float partial = 0.f;
        #pragma unroll
        for (int r = 0; r < 4; r++) {
            const int t = g1 * 4 + r;
            const float tf = (float)t;
            float coef = tf * cw1 - (7.0f - tf);
            if (t <= 6) coef += (tf + 1.0f) * cw0;
            if (t >= 1) coef += (tf - 1.0f) * cw2;
            partial += coef * hv[r];
        }
        const float res = cb + (partial + __shfl_xor(partial, 16)) * (1.0f / 28.0f);
        #pragma unroll
        for (int r = 0; r < 4; r++)
            gq[(size_t)(row + r) * CA + c] = f2bf(gelu_exact(hv[r] + res));
        if (l == 1) {   // out token 0 = gelu(h[l=1]), no res
            #pragma unroll
            for (int r = 0; r < 4; r++)
                gq[(size_t)(row - 128 + r) * CA + c] = f2bf(gelu_exact(hv[r]));
        }
    }
}

// ---------------------------------------------------------------------------
// GEMM2 zero-LDS zero-barrier: out = x + g @ w2 + b2. M=25216, K=192, N=768.
// Wave tile 32x64 (2m x 4n MFMA tiles), block 2x2 waves = 64x128, grid (394,6).
// A (g) and B (w2T) frags direct from global (both L2/L3-resident), reg dbuf,
// K fully unrolled (6 steps). Epilogue streams x residual + writes out.
// ---------------------------------------------------------------------------
__global__ __launch_bounds__(256) void gemm2_kernel(
        const short* __restrict__ gq, const short* __restrict__ w2T,
        const float* __restrict__ b2, const float* __restrict__ x,
        float* __restrict__ out) {
    const int m0 = blockIdx.x * 64, n0 = blockIdx.y * 128;
    const int wave = threadIdx.x >> 6, lane = threadIdx.x & 63;
    const int wm = wave & 1, wn = wave >> 1;
    const int lm = lane & 15, lg = lane >> 4;
    const int mw = m0 + wm * 32, nw = n0 + wn * 64;

    const short* gA  = gq  + (size_t)(mw + lm) * CA + lg * 8;
    const short* wBp = w2T + (size_t)(nw + lm) * CA + lg * 8;

    f32x4 acc[2][4] = {};
    short8 ac[2], bc[4];
    #pragma unroll
    for (int i = 0; i < 2; i++) ac[i] = *(const short8*)(gA + i * 16 * CA);
    #pragma unroll
    for (int j = 0; j < 4; j++) bc[j] = *(const short8*)(wBp + j * 16 * CA);

    #pragma unroll
    for (int k = 0; k < 6; k++) {
        short8 an[2], bn[4];
        if (k < 5) {
            #pragma unroll
            for (int i = 0; i < 2; i++) an[i] = *(const short8*)(gA + i * 16 * CA + (k + 1) * 32);
            #pragma unroll
            for (int j = 0; j < 4; j++) bn[j] = *(const short8*)(wBp + j * 16 * CA + (k + 1) * 32);
        }
        #pragma unroll
        for (int i = 0; i < 2; i++)
            #pragma unroll
            for (int j = 0; j < 4; j++)
                acc[i][j] = __builtin_amdgcn_mfma_f32_16x16x32_bf16(ac[i], bc[j], acc[i][j], 0, 0, 0);
        #pragma unroll
        for (int i = 0; i < 2; i++) ac[i] = an[i];
        #pragma unroll
        for (int j = 0; j < 4; j++) bc[j] = bn[j];
    }

    #pragma unroll
    for (int i = 0; i < 2; i++) {
        const int row0 = mw + i * 16 + lg * 4;
        #pragma unroll
        for (int j = 0; j < 4; j++) {
            const int col = nw + j * 16 + lm;
            const float bias = b2[col];
            #pragma unroll
            for (int r = 0; r < 4; r++) {
                const size_t idx = (size_t)(row0 + r) * DIM + col;
                out[idx] = acc[i][j][r] + x[idx] + bias;
            }
        }
    }
}

// ---------------------------------------------------------------------------
extern "C" void kernel_launch(void* const* d_in, const int* in_sizes, int n_in,
                              void* d_out, int out_size, void* d_ws, size_t ws_size,
                              hipStream_t stream) {
    (void)in_sizes; (void)n_in; (void)out_size; (void)ws_size;
    const float* x      = (const float*)d_in[0];
    const float* w1     = (const float*)d_in[1];
    const float* b1     = (const float*)d_in[2];
    const float* conv_w = (const float*)d_in[3];
    const float* conv_b = (const float*)d_in[4];
    const float* w2     = (const float*)d_in[5];
    const float* b2     = (const float*)d_in[6];
    float* out = (float*)d_out;

    char* ws = (char*)d_ws;
    short* g   = (short*)ws;                           // 25216*192*2 = 9,682,944 B
    short* w1T = (short*)(ws + 9682944);               // 294,912 B
    short* w2T = (short*)(ws + 9682944 + 294912);      // 294,912 B

    prep_kernel<<<(CA * DIM + 255) / 256, 256, 0, stream>>>(w1, w2, w1T, w2T);
    gemm1_fused<<<392, 256, 0, stream>>>(x, w1T, b1, conv_w, conv_b, g);
    gemm2_kernel<<<dim3(394, 6), 256, 0, stream>>>(g, w2T, b2, x, out);
}